// Round 9
// baseline (62.751 us; speedup 1.0000x reference)
//
#include <hip/hip_runtime.h>

// CRPS loss: out = mean(|y_pred - y|) - sum_{i,k,l}|x[i,k]-x[i,l]| / (N*2*M^2)
// N=4096 rows, M=256 ensemble.
//
// R8 post-mortem: 62.6us = ~52us harness floor + k1 ~5.5 + k2 ~2.5. k1's
// compute is at the ISA floor (134M unordered pairs x 2 VALU instr; no
// packed-fp32 abs path on gfx950). R9 trims the only remaining structural
// fat: k1 is now BARRIER-FREE — each wave's lane 0 stores its row partial
// directly (4096 partials), no wsum LDS round-trip, no __syncthreads.
// k2 reduces 4096 floats (4 coalesced float4 per thread).
//
// Pair accounting (64 tiles of 4 elems, lane t owns tile t):
//   s=1..31: tile-pair (t, t+s mod 64) -> each unordered inter-tile pair once
//   s=32:    each d=32 pair appears in both orders -> weight 0.5
//   intra-tile: 6 pairs, once
//   mix_ordered = 2*(m_intra + m_inter) + m32
// Loop structure is remainder-free (R7 lesson: partial-unroll epilogue x
// "+v" inline-asm accumulator miscompiles): s=1..24 unroll 8, s=25..31 full.

constexpr int N_ROWS = 4096;
constexpr int M_COLS = 256;
constexpr int ROWS_PER_BLOCK = 4;                    // 4 waves x 1 row
constexpr int NUM_BLOCKS = N_ROWS / ROWS_PER_BLOCK;  // 1024

// m += |a - b| as exactly 2 VALU instrs (v_sub + v_add with |.| modifier).
__device__ __forceinline__ void abs_acc(float& m, float a, float b) {
    float t = a - b;
    asm("v_add_f32 %0, %0, |%1|" : "+v"(m) : "v"(t));
}

__global__ __launch_bounds__(256)
void crps_partial(const float* __restrict__ y_pred,
                  const float* __restrict__ y,
                  float* __restrict__ partial) {
    __shared__ __align__(16) float4 rows[ROWS_PER_BLOCK][2 * M_COLS / 4];

    const int wave = threadIdx.x >> 6;               // 0..3 -> row of block
    const int lane = threadIdx.x & 63;
    const int row  = blockIdx.x * ROWS_PER_BLOCK + wave;

    // Lane owns tile t=lane (elements 4t..4t+3); stage row twice so rotated
    // reads r4[lane+s] never wrap mod 64.
    const float4 xk = reinterpret_cast<const float4*>(y_pred + row * M_COLS)[lane];
    rows[wave][lane]      = xk;
    rows[wave][lane + 64] = xk;
    const float yi = y[row];                         // wave-uniform

    const float xo[4] = {xk.x, xk.y, xk.z, xk.w};

    // MAE term.
    float mae = 0.0f;
    #pragma unroll
    for (int j = 0; j < 4; ++j) abs_acc(mae, xo[j], yi);

    // 4 independent accumulator chains; intra-tile pairs spread across them.
    float m[4] = {0.0f, 0.0f, 0.0f, 0.0f};
    abs_acc(m[0], xo[0], xo[1]); abs_acc(m[1], xo[0], xo[2]);
    abs_acc(m[2], xo[0], xo[3]); abs_acc(m[3], xo[1], xo[2]);
    abs_acc(m[0], xo[1], xo[3]); abs_acc(m[1], xo[2], xo[3]);

    // No barrier anywhere: wave reads only LDS it wrote itself (same-wave DS
    // ordering) — pattern proven R3/R4/R6/R8.
    const float4* r4 = &rows[wave][lane];            // r4[s] -> imm offset 16s

    // s = 1..24: exactly 3 chunks of 8 — NO remainder epilogue.
    #pragma unroll 8
    for (int s = 1; s <= 24; ++s) {
        const float4 v = r4[s];
        #pragma unroll
        for (int j = 0; j < 4; ++j) {
            abs_acc(m[j], xo[j], v.x); abs_acc(m[j], xo[j], v.y);
            abs_acc(m[j], xo[j], v.z); abs_acc(m[j], xo[j], v.w);
        }
    }
    // s = 25..31: straight-line full unroll — NO remainder epilogue.
    #pragma unroll
    for (int s = 25; s <= 31; ++s) {
        const float4 v = r4[s];
        #pragma unroll
        for (int j = 0; j < 4; ++j) {
            abs_acc(m[j], xo[j], v.x); abs_acc(m[j], xo[j], v.y);
            abs_acc(m[j], xo[j], v.z); abs_acc(m[j], xo[j], v.w);
        }
    }
    // s = 32: every pair counted in both orders across the wave -> weight 0.5.
    float m32 = 0.0f;
    {
        const float4 v = r4[32];
        #pragma unroll
        for (int j = 0; j < 4; ++j) {
            abs_acc(m32, xo[j], v.x); abs_acc(m32, xo[j], v.y);
            abs_acc(m32, xo[j], v.z); abs_acc(m32, xo[j], v.w);
        }
    }

    const float msum = (m[0] + m[1]) + (m[2] + m[3]);

    // mix contribution = (2*msum + m32)/(2*N*M^2) = (msum + 0.5*m32)/(N*M^2)
    constexpr float mae_scale = 1.0f / ((float)N_ROWS * (float)M_COLS);
    constexpr float inv_NM2   = 1.0f / ((float)N_ROWS * (float)M_COLS * (float)M_COLS);
    float part = mae * mae_scale - (msum + 0.5f * m32) * inv_NM2;

    // Wave reduction; lane 0 stores the ROW partial directly (no LDS/barrier).
    #pragma unroll
    for (int off = 32; off > 0; off >>= 1)
        part += __shfl_down(part, off, 64);

    if (lane == 0) partial[row] = part;
}

__global__ __launch_bounds__(256)
void crps_final(const float* __restrict__ partial, float* __restrict__ out) {
    __shared__ float wsum[4];
    const int t = threadIdx.x;
    // 4096 partials = 1024 float4; each thread sums 4 coalesced float4s.
    const float4* p4 = reinterpret_cast<const float4*>(partial);
    float v = 0.0f;
    #pragma unroll
    for (int i = 0; i < 4; ++i) {
        const float4 w = p4[t + 256 * i];
        v += (w.x + w.y) + (w.z + w.w);
    }
    #pragma unroll
    for (int off = 32; off > 0; off >>= 1)
        v += __shfl_down(v, off, 64);
    if ((t & 63) == 0) wsum[t >> 6] = v;
    __syncthreads();
    if (t == 0)
        *out = (wsum[0] + wsum[1]) + (wsum[2] + wsum[3]);
}

extern "C" void kernel_launch(void* const* d_in, const int* in_sizes, int n_in,
                              void* d_out, int out_size, void* d_ws, size_t ws_size,
                              hipStream_t stream) {
    const float* y_pred = (const float*)d_in[0];
    const float* y      = (const float*)d_in[1];
    float* out          = (float*)d_out;
    float* ws           = (float*)d_ws;              // 4096 floats used

    crps_partial<<<NUM_BLOCKS, 256, 0, stream>>>(y_pred, y, ws);
    crps_final<<<1, 256, 0, stream>>>(ws, out);
}